// Round 2
// baseline (635.911 us; speedup 1.0000x reference)
//
#include <hip/hip_runtime.h>
#include <math.h>

// Problem constants (fixed by setup_inputs)
#define BB 2            // batch
#define CC 192          // channels per q/k/v
#define NHEADS 6
#define HD 32           // head dim
#define NTOK 64         // tokens per window (8x8)
#define HDIM 256
#define WDIM 256
#define HWSZ 65536      // H*W
#define NWSIDE 32       // windows per side
#define NW 1024         // windows per image
#define NBLK 12288      // 2048 windows * 6 heads
#define LOGIT_MAX_F 4.605170185988091f   // log(100)
#define INV_SQRT_HD 0.17677669529663687f // 1/sqrt(32)

// ---------------- kernel 1: CPB MLP: relu(table@w1+b1)@w2 -> 16*sigmoid ----
__global__ void cpb_mlp_kernel(const float* __restrict__ table,
                               const float* __restrict__ w1,
                               const float* __restrict__ b1,
                               const float* __restrict__ w2,
                               float* __restrict__ sig16) {
    int t = threadIdx.x;
    if (t >= 225) return;
    float t0 = table[t * 2 + 0];
    float t1 = table[t * 2 + 1];
    float acc[NHEADS] = {0.f, 0.f, 0.f, 0.f, 0.f, 0.f};
    for (int j = 0; j < 512; j++) {
        float h = fmaf(t0, w1[j], fmaf(t1, w1[512 + j], b1[j]));
        h = fmaxf(h, 0.f);
#pragma unroll
        for (int o = 0; o < NHEADS; o++)
            acc[o] = fmaf(h, w2[j * NHEADS + o], acc[o]);
    }
#pragma unroll
    for (int o = 0; o < NHEADS; o++)
        sig16[t * NHEADS + o] = 16.f / (1.f + expf(-acc[o]));
}

// ---------------- kernel 2: gather bias6[h][n][m] = sig16[index[n][m]][h] --
__global__ void cpb_gather_kernel(const int* __restrict__ index,
                                  const float* __restrict__ sig16,
                                  float* __restrict__ bias6) {
    int tid = blockIdx.x * 256 + threadIdx.x;  // 24576 total
    int h = tid >> 12;        // /4096
    int nm = tid & 4095;
    bias6[tid] = sig16[index[nm] * NHEADS + h];
}

// ---------------- kernel 3: fused shifted-window attention -----------------
// logical block = (window, head); block = 64 threads (1 wave); thread = row n.
// T1 XCD swizzle: physical bx -> XCD bx%8 (round-robin). Remap so each XCD
// owns a contiguous chunk of logical blocks: the 4 windows sharing each
// 128B line (delta<=24 logical ids) + 6 heads of a window then share one L2
// -> full-line write coalescing + read reuse in L2 instead of L3.
__global__ __launch_bounds__(64) void win_attn_kernel(
    const float* __restrict__ qkv, const float* __restrict__ mask,
    const float* __restrict__ bias6, const float* __restrict__ logit_scale,
    float* __restrict__ out) {
    // pad rows 32 -> 36 floats: 144B stride keeps float4 alignment and
    // breaks the stride-32 same-bank pattern on the staging ds_writes.
    __shared__ __align__(16) float lk[NTOK][36];
    __shared__ __align__(16) float lv[NTOK][36];

    // bijective XCD-chunk swizzle (NBLK % 8 == 0)
    int bx = (blockIdx.x & 7) * (NBLK / 8) + (blockIdx.x >> 3);

    int head = bx % NHEADS;   // consecutive logical blocks: 6 heads of one window
    int win = bx / NHEADS;
    int b = win >> 10;        // / NW
    int wi = win & (NW - 1);
    int wh = wi >> 5, ww = wi & (NWSIDE - 1);

    int n = threadIdx.x;      // token / attention row
    int i = n >> 3, j = n & 7;
    // roll(-4) before partition and roll(+4) after reverse use the SAME map:
    int hs = (wh * 8 + i + 4) & (HDIM - 1);
    int wsc = (ww * 8 + j + 4) & (WDIM - 1);
    int pix = hs * WDIM + wsc;

    const size_t SPL = (size_t)BB * CC * HWSZ;   // stride between q/k/v planes
    size_t base = ((size_t)b * CC + head * HD) * HWSZ + (size_t)pix;
    const float* qp = qkv + base;
    const float* kp = qkv + SPL + base;
    const float* vp = qkv + 2 * SPL + base;

    // ---- stage: q -> regs, k/v -> LDS (lane n owns token n) ----
    float qreg[HD];
#pragma unroll
    for (int cq = 0; cq < HD; cq += 4) {
        float4 kk, vv;
        kk.x = kp[(size_t)(cq + 0) * HWSZ];
        kk.y = kp[(size_t)(cq + 1) * HWSZ];
        kk.z = kp[(size_t)(cq + 2) * HWSZ];
        kk.w = kp[(size_t)(cq + 3) * HWSZ];
        vv.x = vp[(size_t)(cq + 0) * HWSZ];
        vv.y = vp[(size_t)(cq + 1) * HWSZ];
        vv.z = vp[(size_t)(cq + 2) * HWSZ];
        vv.w = vp[(size_t)(cq + 3) * HWSZ];
        *(float4*)&lk[n][cq] = kk;
        *(float4*)&lv[n][cq] = vv;
        qreg[cq + 0] = qp[(size_t)(cq + 0) * HWSZ];
        qreg[cq + 1] = qp[(size_t)(cq + 1) * HWSZ];
        qreg[cq + 2] = qp[(size_t)(cq + 2) * HWSZ];
        qreg[cq + 3] = qp[(size_t)(cq + 3) * HWSZ];
    }
    __syncthreads();

    // ---- p[m] = bias + mask (float4 loads), then += scale * (q . k[m]) ----
    float p[NTOK];
    const float4* brow = (const float4*)(bias6 + ((size_t)head * NTOK + n) * NTOK);
    const float4* mrow = (const float4*)(mask + ((size_t)wi * NTOK + n) * NTOK);
#pragma unroll
    for (int m4 = 0; m4 < 16; m4++) {
        float4 bbv = brow[m4];
        float4 mmv = mrow[m4];
        p[4 * m4 + 0] = bbv.x + mmv.x;
        p[4 * m4 + 1] = bbv.y + mmv.y;
        p[4 * m4 + 2] = bbv.z + mmv.z;
        p[4 * m4 + 3] = bbv.w + mmv.w;
    }

    float sc = expf(fminf(logit_scale[head], LOGIT_MAX_F)) * INV_SQRT_HD;

    // ---- QK^T: k rows read wave-uniform from LDS (broadcast, no conflict) --
#pragma unroll
    for (int m = 0; m < NTOK; m++) {
        const float4* kr = (const float4*)(&lk[m][0]);
        float d0 = 0.f, d1 = 0.f, d2 = 0.f, d3 = 0.f;
#pragma unroll
        for (int c4 = 0; c4 < 8; c4++) {
            float4 kk = kr[c4];
            d0 = fmaf(qreg[4 * c4 + 0], kk.x, d0);
            d1 = fmaf(qreg[4 * c4 + 1], kk.y, d1);
            d2 = fmaf(qreg[4 * c4 + 2], kk.z, d2);
            d3 = fmaf(qreg[4 * c4 + 3], kk.w, d3);
        }
        p[m] = fmaf((d0 + d1) + (d2 + d3), sc, p[m]);
    }

    // ---- softmax: fully thread-local (thread owns the whole row) ----
    float mx = -1e30f;
#pragma unroll
    for (int m = 0; m < NTOK; m++) mx = fmaxf(mx, p[m]);
    float s0 = 0.f, s1 = 0.f, s2 = 0.f, s3 = 0.f;
#pragma unroll
    for (int m4 = 0; m4 < 16; m4++) {
        float e0 = __expf(p[4 * m4 + 0] - mx);
        float e1 = __expf(p[4 * m4 + 1] - mx);
        float e2 = __expf(p[4 * m4 + 2] - mx);
        float e3 = __expf(p[4 * m4 + 3] - mx);
        p[4 * m4 + 0] = e0; s0 += e0;
        p[4 * m4 + 1] = e1; s1 += e1;
        p[4 * m4 + 2] = e2; s2 += e2;
        p[4 * m4 + 3] = e3; s3 += e3;
    }
    float inv = 1.f / ((s0 + s1) + (s2 + s3));

    // ---- PV: v rows broadcast from LDS ----
    float o[HD];
#pragma unroll
    for (int cc = 0; cc < HD; cc++) o[cc] = 0.f;
#pragma unroll
    for (int m = 0; m < NTOK; m++) {
        const float4* vr = (const float4*)(&lv[m][0]);
        float pm = p[m];
#pragma unroll
        for (int c4 = 0; c4 < 8; c4++) {
            float4 vv = vr[c4];
            o[4 * c4 + 0] = fmaf(pm, vv.x, o[4 * c4 + 0]);
            o[4 * c4 + 1] = fmaf(pm, vv.y, o[4 * c4 + 1]);
            o[4 * c4 + 2] = fmaf(pm, vv.z, o[4 * c4 + 2]);
            o[4 * c4 + 3] = fmaf(pm, vv.w, o[4 * c4 + 3]);
        }
    }

    // ---- write out (same pixel map as input; window-reverse+roll fused) ----
    float* op = out + ((size_t)b * CC + head * HD) * HWSZ + (size_t)pix;
#pragma unroll
    for (int cc = 0; cc < HD; cc++)
        op[(size_t)cc * HWSZ] = o[cc] * inv;
}

extern "C" void kernel_launch(void* const* d_in, const int* in_sizes, int n_in,
                              void* d_out, int out_size, void* d_ws, size_t ws_size,
                              hipStream_t stream) {
    const float* qkv         = (const float*)d_in[0];
    const float* table       = (const float*)d_in[1];
    const int*   index       = (const int*)d_in[2];
    const float* mask        = (const float*)d_in[3];
    const float* logit_scale = (const float*)d_in[4];
    const float* w1          = (const float*)d_in[5];
    const float* b1          = (const float*)d_in[6];
    const float* w2          = (const float*)d_in[7];
    float* out = (float*)d_out;

    // workspace: sig16 (225*6 floats) then bias6 (6*64*64 floats, 16B aligned)
    float* sig16 = (float*)d_ws;
    float* bias6 = sig16 + 1352;  // 225*6=1350, round to 16B boundary

    hipLaunchKernelGGL(cpb_mlp_kernel, dim3(1), dim3(256), 0, stream,
                       table, w1, b1, w2, sig16);
    hipLaunchKernelGGL(cpb_gather_kernel, dim3(96), dim3(256), 0, stream,
                       index, sig16, bias6);
    hipLaunchKernelGGL(win_attn_kernel, dim3(NBLK), dim3(64), 0, stream,
                       qkv, mask, bias6, logit_scale, out);
}

// Round 3
// 578.163 us; speedup vs baseline: 1.0999x; 1.0999x over previous
//
#include <hip/hip_runtime.h>
#include <math.h>

// Problem constants (fixed by setup_inputs)
#define BB 2            // batch
#define CC 192          // channels per q/k/v
#define NHEADS 6
#define HD 32           // head dim
#define NTOK 64         // tokens per window (8x8)
#define HDIM 256
#define WDIM 256
#define HWSZ 65536      // H*W
#define NWSIDE 32       // windows per side
#define NW 1024         // windows per image
#define NBLK 12288      // 2048 windows * 6 heads
#define LOGIT_MAX_F 4.605170185988091f   // log(100)
#define INV_SQRT_HD 0.17677669529663687f // 1/sqrt(32)

// ---------------- kernel 1: CPB MLP: relu(table@w1+b1)@w2 -> 16*sigmoid ----
// R2 fix: was 1 block (1 CU busy, ~375us serial-latency). Now 225 blocks x
// 64 lanes; lane-strided hidden loop (8 iters) + butterfly shfl reduce.
__global__ __launch_bounds__(64) void cpb_mlp_kernel(
    const float* __restrict__ table, const float* __restrict__ w1,
    const float* __restrict__ b1, const float* __restrict__ w2,
    float* __restrict__ sig16) {
    int t = blockIdx.x;      // table entry 0..224
    int lane = threadIdx.x;  // 0..63
    float t0 = table[t * 2 + 0];
    float t1 = table[t * 2 + 1];
    float acc[NHEADS] = {0.f, 0.f, 0.f, 0.f, 0.f, 0.f};
#pragma unroll
    for (int jj = 0; jj < 8; jj++) {
        int j = lane + jj * 64;
        float h = fmaf(t0, w1[j], fmaf(t1, w1[512 + j], b1[j]));
        h = fmaxf(h, 0.f);
#pragma unroll
        for (int o = 0; o < NHEADS; o++)
            acc[o] = fmaf(h, w2[j * NHEADS + o], acc[o]);
    }
#pragma unroll
    for (int o = 0; o < NHEADS; o++) {
        float v = acc[o];
#pragma unroll
        for (int s = 32; s > 0; s >>= 1) v += __shfl_xor(v, s, 64);
        if (lane == 0) sig16[t * NHEADS + o] = 16.f / (1.f + expf(-v));
    }
}

// ---------------- kernel 2: gather bias6[h][n][m] = sig16[index[n][m]][h] --
__global__ void cpb_gather_kernel(const int* __restrict__ index,
                                  const float* __restrict__ sig16,
                                  float* __restrict__ bias6) {
    int tid = blockIdx.x * 256 + threadIdx.x;  // 24576 total
    int h = tid >> 12;        // /4096
    int nm = tid & 4095;
    bias6[tid] = sig16[index[nm] * NHEADS + h];
}

// ---------------- kernel 3: fused shifted-window attention -----------------
// logical block = (window, head); block = 64 threads (1 wave); thread = row n.
// __launch_bounds__(64, 2): min 2 waves/EU -> VGPR cap 256. R2's default
// build chose 96 VGPRs (< ~110 live across softmax: p[64]+o[32]+addr) and
// spilled to scratch; LDS (18.4KB -> 8 blocks/CU = 2/SIMD) caps occupancy
// anyway, so 256 VGPRs cost nothing.
__global__ __launch_bounds__(64, 2) void win_attn_kernel(
    const float* __restrict__ qkv, const float* __restrict__ mask,
    const float* __restrict__ bias6, const float* __restrict__ logit_scale,
    float* __restrict__ out) {
    // pad rows 32 -> 36 floats: 144B stride keeps float4 alignment and
    // breaks the stride-32 same-bank pattern on the staging ds_writes.
    __shared__ __align__(16) float lk[NTOK][36];
    __shared__ __align__(16) float lv[NTOK][36];

    // bijective XCD-chunk swizzle (NBLK % 8 == 0): co-locate the 6 heads of
    // a window + the 4 windows sharing each 128B line on one XCD's L2.
    int bx = (blockIdx.x & 7) * (NBLK / 8) + (blockIdx.x >> 3);

    int head = bx % NHEADS;
    int win = bx / NHEADS;
    int b = win >> 10;        // / NW
    int wi = win & (NW - 1);
    int wh = wi >> 5, ww = wi & (NWSIDE - 1);

    int n = threadIdx.x;      // token / attention row
    int i = n >> 3, j = n & 7;
    // roll(-4) before partition and roll(+4) after reverse use the SAME map:
    int hs = (wh * 8 + i + 4) & (HDIM - 1);
    int wsc = (ww * 8 + j + 4) & (WDIM - 1);
    int pix = hs * WDIM + wsc;

    const size_t SPL = (size_t)BB * CC * HWSZ;   // stride between q/k/v planes
    size_t base = ((size_t)b * CC + head * HD) * HWSZ + (size_t)pix;
    const float* qp = qkv + base;
    const float* kp = qkv + SPL + base;
    const float* vp = qkv + 2 * SPL + base;

    // ---- stage: q -> regs, k/v -> LDS (lane n owns token n) ----
    float qreg[HD];
#pragma unroll
    for (int cq = 0; cq < HD; cq += 4) {
        float4 kk, vv;
        kk.x = kp[(size_t)(cq + 0) * HWSZ];
        kk.y = kp[(size_t)(cq + 1) * HWSZ];
        kk.z = kp[(size_t)(cq + 2) * HWSZ];
        kk.w = kp[(size_t)(cq + 3) * HWSZ];
        vv.x = vp[(size_t)(cq + 0) * HWSZ];
        vv.y = vp[(size_t)(cq + 1) * HWSZ];
        vv.z = vp[(size_t)(cq + 2) * HWSZ];
        vv.w = vp[(size_t)(cq + 3) * HWSZ];
        *(float4*)&lk[n][cq] = kk;
        *(float4*)&lv[n][cq] = vv;
        qreg[cq + 0] = qp[(size_t)(cq + 0) * HWSZ];
        qreg[cq + 1] = qp[(size_t)(cq + 1) * HWSZ];
        qreg[cq + 2] = qp[(size_t)(cq + 2) * HWSZ];
        qreg[cq + 3] = qp[(size_t)(cq + 3) * HWSZ];
    }
    __syncthreads();

    // ---- p[m] = bias + mask (float4 loads), then += scale * (q . k[m]) ----
    float p[NTOK];
    const float4* brow = (const float4*)(bias6 + ((size_t)head * NTOK + n) * NTOK);
    const float4* mrow = (const float4*)(mask + ((size_t)wi * NTOK + n) * NTOK);
#pragma unroll
    for (int m4 = 0; m4 < 16; m4++) {
        float4 bbv = brow[m4];
        float4 mmv = mrow[m4];
        p[4 * m4 + 0] = bbv.x + mmv.x;
        p[4 * m4 + 1] = bbv.y + mmv.y;
        p[4 * m4 + 2] = bbv.z + mmv.z;
        p[4 * m4 + 3] = bbv.w + mmv.w;
    }

    float sc = expf(fminf(logit_scale[head], LOGIT_MAX_F)) * INV_SQRT_HD;

    // ---- QK^T: k rows read wave-uniform from LDS (broadcast, no conflict) --
#pragma unroll
    for (int m = 0; m < NTOK; m++) {
        const float4* kr = (const float4*)(&lk[m][0]);
        float d0 = 0.f, d1 = 0.f, d2 = 0.f, d3 = 0.f;
#pragma unroll
        for (int c4 = 0; c4 < 8; c4++) {
            float4 kk = kr[c4];
            d0 = fmaf(qreg[4 * c4 + 0], kk.x, d0);
            d1 = fmaf(qreg[4 * c4 + 1], kk.y, d1);
            d2 = fmaf(qreg[4 * c4 + 2], kk.z, d2);
            d3 = fmaf(qreg[4 * c4 + 3], kk.w, d3);
        }
        p[m] = fmaf((d0 + d1) + (d2 + d3), sc, p[m]);
    }

    // ---- softmax: fully thread-local (thread owns the whole row) ----
    float mx = -1e30f;
#pragma unroll
    for (int m = 0; m < NTOK; m++) mx = fmaxf(mx, p[m]);
    float s0 = 0.f, s1 = 0.f, s2 = 0.f, s3 = 0.f;
#pragma unroll
    for (int m4 = 0; m4 < 16; m4++) {
        float e0 = __expf(p[4 * m4 + 0] - mx);
        float e1 = __expf(p[4 * m4 + 1] - mx);
        float e2 = __expf(p[4 * m4 + 2] - mx);
        float e3 = __expf(p[4 * m4 + 3] - mx);
        p[4 * m4 + 0] = e0; s0 += e0;
        p[4 * m4 + 1] = e1; s1 += e1;
        p[4 * m4 + 2] = e2; s2 += e2;
        p[4 * m4 + 3] = e3; s3 += e3;
    }
    float inv = 1.f / ((s0 + s1) + (s2 + s3));

    // ---- PV: v rows broadcast from LDS ----
    float o[HD];
#pragma unroll
    for (int cc = 0; cc < HD; cc++) o[cc] = 0.f;
#pragma unroll
    for (int m = 0; m < NTOK; m++) {
        const float4* vr = (const float4*)(&lv[m][0]);
        float pm = p[m];
#pragma unroll
        for (int c4 = 0; c4 < 8; c4++) {
            float4 vv = vr[c4];
            o[4 * c4 + 0] = fmaf(pm, vv.x, o[4 * c4 + 0]);
            o[4 * c4 + 1] = fmaf(pm, vv.y, o[4 * c4 + 1]);
            o[4 * c4 + 2] = fmaf(pm, vv.z, o[4 * c4 + 2]);
            o[4 * c4 + 3] = fmaf(pm, vv.w, o[4 * c4 + 3]);
        }
    }

    // ---- write out (same pixel map as input; window-reverse+roll fused) ----
    float* op = out + ((size_t)b * CC + head * HD) * HWSZ + (size_t)pix;
#pragma unroll
    for (int cc = 0; cc < HD; cc++)
        op[(size_t)cc * HWSZ] = o[cc] * inv;
}

extern "C" void kernel_launch(void* const* d_in, const int* in_sizes, int n_in,
                              void* d_out, int out_size, void* d_ws, size_t ws_size,
                              hipStream_t stream) {
    const float* qkv         = (const float*)d_in[0];
    const float* table       = (const float*)d_in[1];
    const int*   index       = (const int*)d_in[2];
    const float* mask        = (const float*)d_in[3];
    const float* logit_scale = (const float*)d_in[4];
    const float* w1          = (const float*)d_in[5];
    const float* b1          = (const float*)d_in[6];
    const float* w2          = (const float*)d_in[7];
    float* out = (float*)d_out;

    // workspace: sig16 (225*6 floats) then bias6 (6*64*64 floats, 16B aligned)
    float* sig16 = (float*)d_ws;
    float* bias6 = sig16 + 1352;  // 225*6=1350, round to 16B boundary

    hipLaunchKernelGGL(cpb_mlp_kernel, dim3(225), dim3(64), 0, stream,
                       table, w1, b1, w2, sig16);
    hipLaunchKernelGGL(cpb_gather_kernel, dim3(96), dim3(256), 0, stream,
                       index, sig16, bias6);
    hipLaunchKernelGGL(win_attn_kernel, dim3(NBLK), dim3(64), 0, stream,
                       qkv, mask, bias6, logit_scale, out);
}